// Round 5
// baseline (329.880 us; speedup 1.0000x reference)
//
#include <hip/hip_runtime.h>
#include <stdint.h>

// SSIM (32,3,512,512) fp32, separable 11x11 Gaussian, sqrt-free rational form.
// v12: async global->LDS DMA pipeline (depth 3), counted vmcnt -- remove the
// two per-step memory waits from the serial chain.
//   v11 post-mortem: VGPR 76, demand 12 waves/CU under the 16 cap, yet occ
//   25% and dur unchanged (192us ~ v9 194 ~ v7 210 across demands 24/24/12)
//   -> occupancy is NOT the lever. Arithmetic: 439k wave-steps / 461k cyc =
//   1 step per 1076 cyc/SIMD vs ~330 issue-cyc of work -> per-step serial
//   chain ~2-3k cyc. The chain contains (a) s_waitcnt vmcnt(0) on 1-step-
//   slack global loads (~600-900cy exposed) and (b) same-step LDS write->
//   read (~200cy). v12 removes both:
//   - global_load_lds DMA row t+3 into LDS slot (t+3)&3 each step; conv
//     reads slot t&3, landed >=3 steps (~1500cy) ago.
//   - counted "s_waitcnt vmcnt(12)" (4 DMAs/step x 3 batches in flight);
//     NEVER vmcnt(0) in the loop (T3/T4 pattern).
//   - uniform vmcnt arithmetic: OOB rows issue 4 dummy DMAs to a dump slot
//     + ds_write zeros; OOB cols: clamped addrs + border-wave zero fixup.
//   - vmcnt(0) ONCE after the loop (DMA must not outlive workgroup LDS).
//   Numerics bit-identical to v11 (same op order) -> absmax 0 expected.
//   Predicted: VGPR 78-100 (gate <=128), ssim_main 60-110us, total ~190-240.
// Carried lessons: no waves_per_eu coercion (v2,v5,v6,v8); fence-only LDS
// ordering within a wave (v10); readfirstlane is int(int), bit-cast floats
// (v4); 256-bin atomic fan-out (v7); multi-wave WGs (v8); VGPR bands
// 64/128/256 gate waves/SIMD (v9,v10); keep inner unroll at 11 (v10).

#define IMG_H 512
#define IMG_W 512
#define WAVE_W 64                    // output cols per wave
#define STRIPE 128                   // output rows per wave
#define HALO 5
#define KW 11
#define N_ROWT (IMG_H / STRIPE)      // 4
#define N_COLT (IMG_W / WAVE_W)      // 8
#define N_TILES (96 * N_ROWT * N_COLT)   // 3072 tiles, one per wave
#define WPB 4                        // waves per workgroup
#define N_BLOCKS (N_TILES / WPB)     // 768
#define T_MAX 143                    // 13*11; t=138..142 drain (zero slots)
#define NBINS 256
#define TOTAL_PIX (32.0f * 3.0f * 512.0f * 512.0f)

__global__ __launch_bounds__(64 * WPB)
void ssim_main(
    const float* __restrict__ img1, const float* __restrict__ img2,
    const float* __restrict__ window, float* __restrict__ bins)
{
    // Per-wave: 4-deep row ring [slot][signal][col], DMA-written (stride-4
    // per lane, so signals are separate float planes 512B apart -> the two
    // per-tap reads pair into ds_read2_b32). Cols 74..127 are junk padding.
    __shared__ float buf_all[WPB][4][2][128];   // 4096 B/wave
    __shared__ float dump_all[WPB][64];         // dummy-DMA target, 256 B/wave

    const int lane = threadIdx.x & 63;
    const int wv   = threadIdx.x >> 6;
    float (* __restrict__ buf)[2][128] = buf_all[wv];
    float* __restrict__ dump = dump_all[wv];

    // 1D gaussian, wave-uniform (SGPRs): g[k] = w[5][k] / sqrt(w[5][5]).
    float g[KW];
    {
        const float inv = rsqrtf(window[5*KW + 5]);
        #pragma unroll
        for (int k = 0; k < KW; ++k)
            g[k] = __int_as_float(
                __builtin_amdgcn_readfirstlane(
                    __float_as_int(window[5*KW + k] * inv)));
    }

    const int b   = blockIdx.x * WPB + wv; // tile index 0..3071
    const int img = b >> 5;                // 4x8 tiles per image
    const int rem = b & 31;
    const int ty  = rem >> 3;              // 0..3 row stripe
    const int tx  = rem & 7;               // 0..7 col stripe
    const int r0  = ty * STRIPE;
    const int x0  = tx * WAVE_W;

    const float* __restrict__ p1 = img1 + (size_t)img * (IMG_H * IMG_W);
    const float* __restrict__ p2 = img2 + (size_t)img * (IMG_H * IMG_W);

    // Clamped per-lane columns. Main: ring cols 0..63 (gx = x0-5+lane).
    // Tail: ring cols 64..127 (gx = x0+59+lane); only cols 64..73 are read.
    // OOB lanes clamp in-bounds (garbage) and get zeroed by the border fixup.
    const int cm = min(max(x0 - HALO + lane, 0), IMG_W - 1);
    const int ct = min(max(x0 + WAVE_W - HALO + lane, 0), IMG_W - 1);

    // Per-lane stream pointers at row gy = r0-5 (advance +IMG_W per step).
    const float* pm1 = p1 + (long)(r0 - HALO) * IMG_W + cm;
    const float* pm2 = p2 + (long)(r0 - HALO) * IMG_W + cm;
    const float* pt1 = p1 + (long)(r0 - HALO) * IMG_W + ct;
    const float* pt2 = p2 + (long)(r0 - HALO) * IMG_W + ct;
    const float* pdm = p1 + lane;          // always-safe dummy source

    // Issue one row-batch (ALWAYS exactly 4 DMAs -> vmcnt stays uniform).
    auto issue = [&](int tl) {
        const int slot = tl & 3;
        float* s0 = &buf[slot][0][0];
        float* s1 = &buf[slot][1][0];
        if ((unsigned)(r0 - HALO + tl) < IMG_H) {    // wave-uniform branch
            __builtin_amdgcn_global_load_lds(pm1, s0,      4, 0, 0);
            __builtin_amdgcn_global_load_lds(pt1, s0 + 64, 4, 0, 0);
            __builtin_amdgcn_global_load_lds(pm2, s1,      4, 0, 0);
            __builtin_amdgcn_global_load_lds(pt2, s1 + 64, 4, 0, 0);
        } else {
            __builtin_amdgcn_global_load_lds(pdm, dump, 4, 0, 0);
            __builtin_amdgcn_global_load_lds(pdm, dump, 4, 0, 0);
            __builtin_amdgcn_global_load_lds(pdm, dump, 4, 0, 0);
            __builtin_amdgcn_global_load_lds(pdm, dump, 4, 0, 0);
            // SAME-padding zeros for the OOB row (in-order DS pipe orders
            // these after the previous step's reads of this slot).
            s0[lane] = 0.f; s0[64 + lane] = 0.f;
            s1[lane] = 0.f; s1[64 + lane] = 0.f;
        }
        pm1 += IMG_W; pm2 += IMG_W; pt1 += IMG_W; pt2 += IMG_W;
    };

    // h-value register ring: 5 signals x 11 slots, all in VGPRs.
    float r_h1[KW], r_h2[KW], r_h11[KW], r_h22[KW], r_h12[KW];
    #pragma unroll
    for (int i = 0; i < KW; ++i) {
        r_h1[i] = 0.f; r_h2[i] = 0.f; r_h11[i] = 0.f; r_h22[i] = 0.f; r_h12[i] = 0.f;
    }

    const float C1 = 1e-4f;
    const float C2 = 9e-4f;
    float sum = 0.f;

    // Prologue: 3 batches in flight (slots 0,1,2 <- rows t=0,1,2).
    issue(0); issue(1); issue(2);

    #pragma unroll 1
    for (int tb = 0; tb < T_MAX; tb += KW) {
        #pragma unroll
        for (int u = 0; u < KW; ++u) {       // ring slot u compile-time
            const int t = tb + u;

            // A) Prefetch row t+3 into slot (t+3)&3; advance pointers.
            issue(t + 3);

            // B) Counted wait: 4 batches outstanding -> drain the oldest
            //    (slot t&3, issued 3 steps ago). Never vmcnt(0) here.
            asm volatile("s_waitcnt vmcnt(12)" ::: "memory");

            // C) Border-column fixup (edge-tile waves only; DS-pipe order +
            //    LDS alias analysis keep these before this step's reads).
            if (tx == 0) {
                if (lane < HALO) {
                    buf[t & 3][0][lane] = 0.f;
                    buf[t & 3][1][lane] = 0.f;
                }
            }
            if (tx == 7) {
                if (lane >= HALO && lane < 2*HALO) {
                    buf[t & 3][0][64 + lane] = 0.f;
                    buf[t & 3][1][64 + lane] = 0.f;
                }
            }

            // D) Horizontal 11-tap conv from slot t&3 (landed long ago).
            const float* bA = &buf[t & 3][0][lane];
            const float* bB = &buf[t & 3][1][lane];
            float h1 = 0.f, h2 = 0.f, h11 = 0.f, h22 = 0.f, h12 = 0.f;
            #pragma unroll
            for (int k = 0; k < KW; ++k) {
                const float va = bA[k];
                const float vb = bB[k];
                const float t1 = g[k] * va;
                const float t2 = g[k] * vb;
                h1  += t1;
                h2  += t2;
                h11 += t1 * va;
                h22 += t2 * vb;
                h12 += t1 * vb;
            }
            // Pin next step's DMA issue below this step's ds_reads.
            asm volatile("" ::: "memory");

            r_h1[u] = h1; r_h2[u] = h2; r_h11[u] = h11; r_h22[u] = h22; r_h12[u] = h12;

            // E) Vertical gather + SSIM for output row r0 + t - 10.
            if (t >= 2*HALO && t < 2*HALO + STRIPE) {
                float mu1 = 0.f, mu2 = 0.f, e11 = 0.f, e22 = 0.f, e12 = 0.f;
                #pragma unroll
                for (int m = 0; m < KW; ++m) {
                    const int slot = (u + 1 + m) % KW;  // compile-time
                    mu1 += g[m] * r_h1[slot];
                    mu2 += g[m] * r_h2[slot];
                    e11 += g[m] * r_h11[slot];
                    e22 += g[m] * r_h22[slot];
                    e12 += g[m] * r_h12[slot];
                }
                const float mu1s = mu1 * mu1, mu2s = mu2 * mu2, mu12 = mu1 * mu2;
                const float s1  = fmaxf(e11 - mu1s, 0.f);
                const float s2  = fmaxf(e22 - mu2s, 0.f);
                const float s12 = e12 - mu12;
                const float num = (2.f * mu12 + C1) * (2.f * s12 + C2);
                const float den = (mu1s + mu2s + C1) * (s1 + s2 + C2);
                sum += num * __builtin_amdgcn_rcpf(den);
            }
        }
    }

    // Drain ALL outstanding DMAs before this workgroup's LDS can be freed.
    asm volatile("s_waitcnt vmcnt(0)" ::: "memory");

    // Per-wave reduction -> one atomicAdd per wave, fanned over 256 bins.
    #pragma unroll
    for (int off = 32; off > 0; off >>= 1)
        sum += __shfl_down(sum, off, 64);
    if (lane == 0)
        atomicAdd(&bins[b & (NBINS - 1)], sum);
}

__global__ __launch_bounds__(64) void ssim_final(
    const float* __restrict__ bins, float* __restrict__ out)
{
    const int tid = threadIdx.x;
    float s = 0.f;
    #pragma unroll
    for (int i = 0; i < NBINS / 64; ++i) s += bins[tid + i * 64];
    #pragma unroll
    for (int off = 32; off > 0; off >>= 1)
        s += __shfl_down(s, off, 64);
    if (tid == 0) out[0] = s * (1.0f / TOTAL_PIX);
}

extern "C" void kernel_launch(void* const* d_in, const int* in_sizes, int n_in,
                              void* d_out, int out_size, void* d_ws, size_t ws_size,
                              hipStream_t stream) {
    const float* img1   = (const float*)d_in[0];
    const float* img2   = (const float*)d_in[1];
    const float* window = (const float*)d_in[2];
    float* bins = (float*)d_ws;
    float* out  = (float*)d_out;

    hipMemsetAsync(bins, 0, NBINS * sizeof(float), stream);
    ssim_main<<<N_BLOCKS, 64 * WPB, 0, stream>>>(img1, img2, window, bins);
    ssim_final<<<1, 64, 0, stream>>>(bins, out);
}

// Round 6
// 320.634 us; speedup vs baseline: 1.0288x; 1.0288x over previous
//
#include <hip/hip_runtime.h>

// SSIM (32,3,512,512) fp32, separable 11x11 Gaussian, sqrt-free rational form.
// v13: pair-row ILP + packed fp32 on the v12 DMA skeleton.
//   v12 post-mortem: removing BOTH memory waits from the chain (DMA depth-3,
//   counted vmcnt) changed nothing (207 vs 192us). v7/v9/v11/v12 = four
//   different memory schedules, all pinned 190-215us, VALUBusy 78-85%, occ
//   25-30%. The invariant is the per-wave serial step loop (143 x 1-row
//   steps, ~350 issue-cyc vs ~2100-3200 cyc wall per step at 2-3 waves/SIMD).
//   Suspects: (A) per-wave ILP too low to cover dep-latency at ~2 resident
//   waves/SIMD; (B) real VALU count ~2.5x my estimate (VALUBusy literal).
//   v13 attacks both:
//   1) TWO rows per iteration: h-ring is SHARED by adjacent rows (11->12
//      slots, +5 regs, not 2x) -> 2x independent chains, 69 iters not 143.
//   2) float2-packed signals -> v_pk_{mul,add,fma}_f32: tap math 7->4 inst,
//      v-gather 5->3 per tap. Same op order/rounding as v11/v12 (pk_add for
//      h1+=t1, contracted pk_fma elsewhere) -> absmax unchanged.
//   Skeleton: LDS ring 6 row-slots (slot=row%6, 12-row blocks -> all slots
//   compile-time), h-ring 12 x {f2,f2,f32} = 60 VGPR, DMA prefetch 4-5 rows
//   ahead, vmcnt(16) counted (never 0 in loop), dead rows -> dummy DMA +
//   zero ds_write, border cols -> predicated zero-writes.
//   Gate: VGPR <= 128. Predicted main: ~95-120us if (A), ~80-100 if (A+B),
//   ~190 unchanged if neither (-> true VALU-bound, reduce work next).
// Carried: no waves_per_eu coercion (v2,5,6,8); fence-only same-wave LDS
// order (v10); readfirstlane int bit-cast (v4); 256-bin fan-out (v7);
// multi-wave WGs (v8); VGPR bands 64/128/256 (v9,v10); moderate unroll (v10).

typedef float f2 __attribute__((ext_vector_type(2)));

#define IMG_H 512
#define IMG_W 512
#define WAVE_W 64
#define STRIPE 128
#define HALO 5
#define KW 11
#define N_ROWT (IMG_H / STRIPE)        // 4
#define N_COLT (IMG_W / WAVE_W)        // 8
#define N_TILES (96 * N_ROWT * N_COLT) // 3072 tiles, one per wave
#define WPB 4
#define N_BLOCKS (N_TILES / WPB)       // 768
#define T_ROWS (STRIPE + 2*HALO)       // 138 input rows per tile
#define NBINS 256
#define TOTAL_PIX (32.0f * 3.0f * 512.0f * 512.0f)

__global__ __launch_bounds__(64 * WPB)
void ssim_main(
    const float* __restrict__ img1, const float* __restrict__ img2,
    const float* __restrict__ window, float* __restrict__ bins)
{
    // Per-wave LDS: 6-deep row ring [slot][signal][col] (cols 74..127 junk
    // pad for DMA), plus a dummy-DMA dump. 6*2*128*4 = 6144 B/wave.
    __shared__ float buf_all[WPB][6][2][128];
    __shared__ float dump_all[WPB][64];

    const int lane = threadIdx.x & 63;
    const int wv   = threadIdx.x >> 6;
    float (* __restrict__ buf)[2][128] = buf_all[wv];
    float* __restrict__ dump = dump_all[wv];

    // 1D gaussian, wave-uniform (SGPRs): g[k] = w[5][k] / sqrt(w[5][5]).
    float g[KW];
    {
        const float inv = rsqrtf(window[5*KW + 5]);
        #pragma unroll
        for (int k = 0; k < KW; ++k)
            g[k] = __int_as_float(
                __builtin_amdgcn_readfirstlane(
                    __float_as_int(window[5*KW + k] * inv)));
    }

    const int b   = blockIdx.x * WPB + wv; // tile index 0..3071
    const int img = b >> 5;                // 4x8 tiles per image
    const int rem = b & 31;
    const int ty  = rem >> 3;              // 0..3 row stripe
    const int tx  = rem & 7;               // 0..7 col stripe
    const int r0  = ty * STRIPE;
    const int x0  = tx * WAVE_W;

    const float* __restrict__ p1 = img1 + (size_t)img * (IMG_H * IMG_W);
    const float* __restrict__ p2 = img2 + (size_t)img * (IMG_H * IMG_W);

    // Clamped per-lane columns (main cols 0..63, tail cols 64..73 read).
    const int cm = min(max(x0 - HALO + lane, 0), IMG_W - 1);
    const int ct = min(max(x0 + WAVE_W - HALO + lane, 0), IMG_W - 1);

    // Stream pointers: always point at the NEXT row to issue.
    const float* pm1 = p1 + (long)(r0 - HALO) * IMG_W + cm;
    const float* pm2 = p2 + (long)(r0 - HALO) * IMG_W + cm;
    const float* pt1 = p1 + (long)(r0 - HALO) * IMG_W + ct;
    const float* pt2 = p2 + (long)(r0 - HALO) * IMG_W + ct;
    const float* pdm = p1 + lane;          // always-safe dummy source

    // Border-column fixup predicates (edge-tile waves only).
    const bool fixL = (tx == 0)        && (lane < HALO);
    const bool fixR = (tx == N_COLT-1) && (lane >= HALO && lane < 2*HALO);

    // h-history ring: 12 rows x {(h1,h2), (h11,h22), h12} = 60 VGPR.
    f2 rab[12], rsq[12];
    float rx[12];
    #pragma unroll
    for (int i = 0; i < 12; ++i) {
        rab[i] = (f2){0.f, 0.f}; rsq[i] = (f2){0.f, 0.f}; rx[i] = 0.f;
    }

    const float C1 = 1e-4f, C2 = 9e-4f;
    float sum = 0.f;

// Issue one row (ALWAYS exactly 4 DMAs -> uniform vmcnt). SLOT compile-time.
#define ISSUE(SLOT, TL) do {                                                  \
        float* s0_ = &buf[(SLOT)][0][0];                                      \
        float* s1_ = &buf[(SLOT)][1][0];                                      \
        const int gy_ = r0 - HALO + (TL);                                     \
        if ((TL) < T_ROWS && (unsigned)gy_ < IMG_H) {                         \
            __builtin_amdgcn_global_load_lds(pm1, s0_,      4, 0, 0);         \
            __builtin_amdgcn_global_load_lds(pt1, s0_ + 64, 4, 0, 0);         \
            __builtin_amdgcn_global_load_lds(pm2, s1_,      4, 0, 0);         \
            __builtin_amdgcn_global_load_lds(pt2, s1_ + 64, 4, 0, 0);         \
        } else {                                                              \
            __builtin_amdgcn_global_load_lds(pdm, dump, 4, 0, 0);             \
            __builtin_amdgcn_global_load_lds(pdm, dump, 4, 0, 0);             \
            __builtin_amdgcn_global_load_lds(pdm, dump, 4, 0, 0);             \
            __builtin_amdgcn_global_load_lds(pdm, dump, 4, 0, 0);             \
            s0_[lane] = 0.f; s0_[64 + lane] = 0.f;                            \
            s1_[lane] = 0.f; s1_[64 + lane] = 0.f;                            \
        }                                                                     \
        pm1 += IMG_W; pm2 += IMG_W; pt1 += IMG_W; pt2 += IMG_W;               \
    } while (0)

// Horizontal 11-tap conv of one row (packed): LSLOT/HS compile-time.
// Same rounding as v11/v12: t=g*v (mul), hab+=t (add), hsq+=t*v (fma),
// hx+=t.x*v.y (fma).
#define HCONV(LSLOT, HS) do {                                                 \
        const float* bA_ = &buf[(LSLOT)][0][lane];                            \
        const float* bB_ = &buf[(LSLOT)][1][lane];                            \
        f2 hab_ = (f2){0.f, 0.f}, hsq_ = (f2){0.f, 0.f};                      \
        float hx_ = 0.f;                                                      \
        _Pragma("unroll")                                                     \
        for (int k = 0; k < KW; ++k) {                                        \
            f2 v_; v_.x = bA_[k]; v_.y = bB_[k];                              \
            const f2 t_ = v_ * g[k];                                          \
            hab_ += t_;                                                       \
            hsq_ += t_ * v_;                                                  \
            hx_  = fmaf(t_.x, v_.y, hx_);                                     \
        }                                                                     \
        rab[(HS)] = hab_; rsq[(HS)] = hsq_; rx[(HS)] = hx_;                   \
    } while (0)

// Vertical gather + SSIM for one output row; OFF compile-time.
#define OUTROW(OFF) do {                                                      \
        f2 mu_ = (f2){0.f, 0.f}, e_ = (f2){0.f, 0.f};                         \
        float e12_ = 0.f;                                                     \
        _Pragma("unroll")                                                     \
        for (int m = 0; m < KW; ++m) {                                        \
            const int s_ = ((OFF) + m) % 12;      /* compile-time */          \
            mu_ += rab[s_] * g[m];                                            \
            e_  += rsq[s_] * g[m];                                            \
            e12_ = fmaf(g[m], rx[s_], e12_);                                  \
        }                                                                     \
        const float mu1s_ = mu_.x * mu_.x;                                    \
        const float mu2s_ = mu_.y * mu_.y;                                    \
        const float mu12_ = mu_.x * mu_.y;                                    \
        const float s1_  = fmaxf(e_.x - mu1s_, 0.f);                          \
        const float s2_  = fmaxf(e_.y - mu2s_, 0.f);                          \
        const float s12_ = e12_ - mu12_;                                      \
        const float num_ = (2.f * mu12_ + C1) * (2.f * s12_ + C2);            \
        const float den_ = (mu1s_ + mu2s_ + C1) * (s1_ + s2_ + C2);           \
        sum += num_ * __builtin_amdgcn_rcpf(den_);                            \
    } while (0)

// One pair-iteration: rows t, t+1 where t = TB + 2*J, TB % 12 == 0.
// LDS slots (row%6) and h slots (row%12) depend only on J -> compile-time.
#define PAIR(J, TB, DOGAT) do {                                               \
        const int t_ = (TB) + 2*(J);                                          \
        ISSUE((2*(J)+4) % 6, t_ + 4);                                         \
        ISSUE((2*(J)+5) % 6, t_ + 5);                                         \
        /* 6 rows (24 DMA) outstanding max; wait oldest 8 -> rows t,t+1. */   \
        asm volatile("s_waitcnt vmcnt(16)" ::: "memory");                     \
        if (fixL) {                                                           \
            buf[(2*(J))%6][0][lane] = 0.f;   buf[(2*(J))%6][1][lane] = 0.f;   \
            buf[(2*(J)+1)%6][0][lane] = 0.f; buf[(2*(J)+1)%6][1][lane] = 0.f; \
        }                                                                     \
        if (fixR) {                                                           \
            buf[(2*(J))%6][0][64+lane] = 0.f;   buf[(2*(J))%6][1][64+lane] = 0.f;   \
            buf[(2*(J)+1)%6][0][64+lane] = 0.f; buf[(2*(J)+1)%6][1][64+lane] = 0.f; \
        }                                                                     \
        HCONV((2*(J))%6,   2*(J));                                            \
        HCONV((2*(J)+1)%6, 2*(J)+1);                                          \
        /* Pin next iter's DMA/zero-writes below this iter's ds_reads. */     \
        asm volatile("" ::: "memory");                                        \
        if (DOGAT) {                                                          \
            OUTROW(2*(J) + 2);   /* output row t-10 */                        \
            OUTROW(2*(J) + 3);   /* output row t-9  */                        \
        }                                                                     \
    } while (0)

    // Prologue: rows 0..3 in flight (16 DMAs), slots 0..3.
    ISSUE(0, 0); ISSUE(1, 1); ISSUE(2, 2); ISSUE(3, 3);

    // Block 0 (t = 0..11): first output pair at j == 5 (t == 10).
    PAIR(0, 0, 0); PAIR(1, 0, 0); PAIR(2, 0, 0);
    PAIR(3, 0, 0); PAIR(4, 0, 0); PAIR(5, 0, 1);

    // Main: 10 blocks of 6 pairs (t = 12..131), all outputs live.
    #pragma unroll 1
    for (int tb = 12; tb < 132; tb += 12) {
        #pragma unroll
        for (int j = 0; j < 6; ++j)
            PAIR(j, tb, 1);
    }

    // Tail: t = 132..137 (3 pairs; prefetches route to dump).
    PAIR(0, 132, 1); PAIR(1, 132, 1); PAIR(2, 132, 1);

#undef PAIR
#undef OUTROW
#undef HCONV
#undef ISSUE

    // Drain all DMAs before the workgroup's LDS can be reused.
    asm volatile("s_waitcnt vmcnt(0)" ::: "memory");

    // Per-wave reduction -> one atomicAdd per wave, fanned over 256 bins.
    #pragma unroll
    for (int off = 32; off > 0; off >>= 1)
        sum += __shfl_down(sum, off, 64);
    if (lane == 0)
        atomicAdd(&bins[b & (NBINS - 1)], sum);
}

__global__ __launch_bounds__(64) void ssim_final(
    const float* __restrict__ bins, float* __restrict__ out)
{
    const int tid = threadIdx.x;
    float s = 0.f;
    #pragma unroll
    for (int i = 0; i < NBINS / 64; ++i) s += bins[tid + i * 64];
    #pragma unroll
    for (int off = 32; off > 0; off >>= 1)
        s += __shfl_down(s, off, 64);
    if (tid == 0) out[0] = s * (1.0f / TOTAL_PIX);
}

extern "C" void kernel_launch(void* const* d_in, const int* in_sizes, int n_in,
                              void* d_out, int out_size, void* d_ws, size_t ws_size,
                              hipStream_t stream) {
    const float* img1   = (const float*)d_in[0];
    const float* img2   = (const float*)d_in[1];
    const float* window = (const float*)d_in[2];
    float* bins = (float*)d_ws;
    float* out  = (float*)d_out;

    hipMemsetAsync(bins, 0, NBINS * sizeof(float), stream);
    ssim_main<<<N_BLOCKS, 64 * WPB, 0, stream>>>(img1, img2, window, bins);
    ssim_final<<<1, 64, 0, stream>>>(bins, out);
}